// Round 2
// baseline (346.239 us; speedup 1.0000x reference)
//
#include <hip/hip_runtime.h>

// GuidedAttentionLoss: out = sum_{b,n,t} W[b,n,t] * A[b,n,t] / B
// W = mask ? 1 - exp(-((n/seq - t/mel)^2) / (2 g^2)) : 0
// A: (B=64, N=512, T=2048) fp32.
// Memory-bound. Ideal traffic ~144 MB (skip rows n>=seq, cols t>=mel).
// Persistent blocks: 2048 blocks x 256 thr (8 blocks/CU), grid-stride over
// rows, per-b reciprocals cached in LDS, register accumulation across rows,
// single block-reduce + one atomicAdd per block.

#define GAL_B 64
#define GAL_N 512
#define GAL_T 2048
#define GAL_GRID 2048

__global__ __launch_bounds__(256) void gal_fused(
    const float* __restrict__ A,
    const float* __restrict__ gptr,
    const int*   __restrict__ mel_lens,
    const int*   __restrict__ seq_lens,
    float*       __restrict__ out)
{
    __shared__ float s_inv_seq[GAL_B];
    __shared__ float s_inv_mel[GAL_B];
    __shared__ int   s_seq[GAL_B];
    __shared__ int   s_mel[GAL_B];

    if (threadIdx.x < GAL_B) {
        const int sq = seq_lens[threadIdx.x];
        const int ml = mel_lens[threadIdx.x];
        s_seq[threadIdx.x]     = sq;
        s_mel[threadIdx.x]     = ml;
        s_inv_seq[threadIdx.x] = 1.0f / (float)sq;
        s_inv_mel[threadIdx.x] = 1.0f / (float)ml;
    }
    __syncthreads();

    const float g      = gptr[0];
    const float inv2g2 = 1.0f / (2.0f * g * g);

    float local = 0.0f;

    for (int row = blockIdx.x; row < GAL_B * GAL_N; row += GAL_GRID) {
        const int b = row >> 9;          // / 512
        const int n = row & (GAL_N - 1);
        const int seq = s_seq[b];
        if (n >= seq) continue;          // zero contribution: skip the loads

        const int   mel     = s_mel[b];
        const float nf      = (float)n * s_inv_seq[b];
        const float inv_mel = s_inv_mel[b];
        const float4* Arow  = (const float4*)(A + ((size_t)row << 11));
        const int nvec = (mel + 3) >> 2;

        for (int j = threadIdx.x; j < nvec; j += 256) {
            const float4 a = Arow[j];
            const int t0 = j << 2;
            {
                float d = nf - (float)(t0 + 0) * inv_mel;
                float w = 1.0f - __expf(-d * d * inv2g2);
                local += (t0 + 0 < mel) ? w * a.x : 0.0f;
            }
            {
                float d = nf - (float)(t0 + 1) * inv_mel;
                float w = 1.0f - __expf(-d * d * inv2g2);
                local += (t0 + 1 < mel) ? w * a.y : 0.0f;
            }
            {
                float d = nf - (float)(t0 + 2) * inv_mel;
                float w = 1.0f - __expf(-d * d * inv2g2);
                local += (t0 + 2 < mel) ? w * a.z : 0.0f;
            }
            {
                float d = nf - (float)(t0 + 3) * inv_mel;
                float w = 1.0f - __expf(-d * d * inv2g2);
                local += (t0 + 3 < mel) ? w * a.w : 0.0f;
            }
        }
    }

    // wave64 butterfly, then cross-wave via LDS, one atomic per block
    #pragma unroll
    for (int off = 32; off > 0; off >>= 1)
        local += __shfl_down(local, off, 64);

    __shared__ float s_red[4];
    const int lane = threadIdx.x & 63;
    const int wave = threadIdx.x >> 6;
    if (lane == 0) s_red[wave] = local;
    __syncthreads();
    if (threadIdx.x == 0) {
        const float blocksum = (s_red[0] + s_red[1]) + (s_red[2] + s_red[3]);
        atomicAdd(out, blocksum * (1.0f / (float)GAL_B));
    }
}

extern "C" void kernel_launch(void* const* d_in, const int* in_sizes, int n_in,
                              void* d_out, int out_size, void* d_ws, size_t ws_size,
                              hipStream_t stream) {
    const float* A        = (const float*)d_in[0];
    const float* g        = (const float*)d_in[1];
    const int*   mel_lens = (const int*)d_in[2];
    const int*   seq_lens = (const int*)d_in[3];
    float* out = (float*)d_out;

    // d_out is poisoned 0xAA before every timed launch; zero it for the atomics.
    hipMemsetAsync(out, 0, sizeof(float) * (size_t)out_size, stream);
    gal_fused<<<GAL_GRID, 256, 0, stream>>>(A, g, mel_lens, seq_lens, out);
}